// Round 1
// 4482.355 us; speedup vs baseline: 1.1153x; 1.1153x over previous
//
#include <hip/hip_runtime.h>
#include <hip/hip_cooperative_groups.h>
#include <cstdint>

namespace cg = cooperative_groups;

typedef unsigned short u16;
typedef __attribute__((ext_vector_type(8))) short bf16x8;   // 8 bf16 = 4 VGPRs
typedef __attribute__((ext_vector_type(4))) float f32x4;
typedef __attribute__((ext_vector_type(4))) unsigned short u16x4;

#define AS_GLOBAL __attribute__((address_space(1)))
#define AS_LDS    __attribute__((address_space(3)))

__device__ __forceinline__ void gld_lds16(const void* g, void* l) {
    // async global->LDS, 16B per lane; LDS dest = wave-uniform base + lane*16
    __builtin_amdgcn_global_load_lds((const AS_GLOBAL unsigned int*)g,
                                     (AS_LDS unsigned int*)l, 16, 0, 0);
}

__device__ __forceinline__ u16 f2bf(float f) {
    union { float f; unsigned int u; } v; v.f = f;
    unsigned int u = v.u;
    u = (u + 0x7FFFu + ((u >> 16) & 1u)) >> 16;   // RNE, no NaNs in this data
    return (u16)u;
}

__device__ __forceinline__ f32x4 mfma16(bf16x8 a, bf16x8 b, f32x4 c) {
    return __builtin_amdgcn_mfma_f32_16x16x32_bf16(a, b, c, 0, 0, 0);
}

__device__ __forceinline__ float sigm(float x) {
    return 1.f / (1.f + __expf(-x));
}

// ---------------------------------------------------------------------------
// C[M,N] = A[M,K](bf16) @ BT[N,K](bf16)^T + bias[N], C fp32.
// M%128==0, N%128==0, K%32==0. Stores only col < Nstore, C row stride ldc.
// m97 structure: 128x128 tile, 4 waves of 64x64, BK=32, global_load_lds x16B.
// ---------------------------------------------------------------------------
__global__ __launch_bounds__(256) void gemm_bt(
    const u16* __restrict__ A, const u16* __restrict__ BT,
    const float* __restrict__ bias, float* __restrict__ C,
    int M, int N, int K, int ldc, int Nstore)
{
    __shared__ u16 As[128 * 32];
    __shared__ u16 Bs[128 * 32];

    const int tid  = threadIdx.x;
    const int lane = tid & 63;
    const int wave = tid >> 6;
    const int quad = lane >> 4;
    const int l16  = lane & 15;
    const int m0 = blockIdx.y * 128;
    const int n0 = blockIdx.x * 128;
    const int wm = (wave >> 1) * 64;
    const int wn = (wave & 1) * 64;

    f32x4 acc[4][4];
#pragma unroll
    for (int i = 0; i < 4; i++)
#pragma unroll
        for (int j = 0; j < 4; j++) acc[i][j] = (f32x4){0.f, 0.f, 0.f, 0.f};

    // staging slots: slot s -> LDS elems [s*8, s*8+8) -> row s>>2, elem col (s&3)*8
    const int s0 = tid, s1 = tid + 256;
    const int r0 = s0 >> 2, c0 = (s0 & 3) * 8;
    const int r1 = s1 >> 2, c1 = (s1 & 3) * 8;

    const u16* ga0 = A  + (size_t)(m0 + r0) * K + c0;
    const u16* ga1 = A  + (size_t)(m0 + r1) * K + c1;
    const u16* gb0 = BT + (size_t)(n0 + r0) * K + c0;
    const u16* gb1 = BT + (size_t)(n0 + r1) * K + c1;
    u16* la0 = &As[s0 * 8];
    u16* la1 = &As[s1 * 8];
    u16* lb0 = &Bs[s0 * 8];
    u16* lb1 = &Bs[s1 * 8];

    const u16* lra = &As[(wm + l16) * 32 + quad * 8];
    const u16* lrb = &Bs[(wn + l16) * 32 + quad * 8];

    const int nk = K >> 5;
    for (int kb = 0; kb < nk; ++kb) {
        const int k0 = kb << 5;
        gld_lds16(ga0 + k0, la0);
        gld_lds16(ga1 + k0, la1);
        gld_lds16(gb0 + k0, lb0);
        gld_lds16(gb1 + k0, lb1);
        __syncthreads();
        bf16x8 a[4], b[4];
#pragma unroll
        for (int i = 0; i < 4; i++) a[i] = *(const bf16x8*)(lra + i * 16 * 32);
#pragma unroll
        for (int j = 0; j < 4; j++) b[j] = *(const bf16x8*)(lrb + j * 16 * 32);
#pragma unroll
        for (int i = 0; i < 4; i++)
#pragma unroll
            for (int j = 0; j < 4; j++)
                acc[i][j] = mfma16(a[i], b[j], acc[i][j]);
        __syncthreads();
    }

#pragma unroll
    for (int i = 0; i < 4; i++) {
#pragma unroll
        for (int r = 0; r < 4; r++) {
            const int row = m0 + wm + i * 16 + quad * 4 + r;
#pragma unroll
            for (int j = 0; j < 4; j++) {
                const int col = n0 + wn + j * 16 + l16;
                if (col < Nstore)
                    C[(size_t)row * ldc + col] = acc[i][j][r] + bias[col];
            }
        }
    }
}

// ---------------------------------------------------------------------------
// Persistent recurrence: all 128 GRU steps in one cooperative kernel.
// Grid = 64 blocks x 256 threads, 1 block/CU (99 KB LDS). Weights pinned in
// LDS once (block b owns WzrT rows [b*32,b*32+32) and WhhT rows [b*16,b*16+16)).
// Per step: phase1 (ZR: N=2048, 2 n-tiles/block, wave=(n-tile,m-tile))
//   -> grid.sync -> phase2 (Htilda+combine: N=1024, 1 n-tile/block,
//   wave=(m-tile,k-half) + LDS reduce) -> grid.sync.
// Row stride padded to 1032 u16 (+16B) so ds_read_b128 at row stride is
// 2-way (free) instead of 16-way bank conflicted.
// ---------------------------------------------------------------------------
#define WPAD 1032

__global__ __launch_bounds__(256) void k_recurrence(
    const u16* __restrict__ WzrT,   // [2048][1024]
    const u16* __restrict__ WhhT,   // [1024][1024]
    const float* __restrict__ Xzrh, // [T*32][3072]
    float* __restrict__ Hf,         // [32][1024] fp32 master H
    u16* __restrict__ Hbf,          // [32][1024] bf16 H
    float* __restrict__ Zbuf,       // [32][1024]
    u16* __restrict__ RHbf,         // [32][1024]
    u16* __restrict__ Hsbf,         // [T][32][1024] bf16 H history
    int T)
{
    __shared__ __align__(16) u16 Wzr_s[32 * WPAD];   // 66 KB
    __shared__ __align__(16) u16 Whh_s[16 * WPAD];   // 33 KB
    __shared__ __align__(16) float red[2][64][4];    // 2 KB k-half reduce

    const int tid  = threadIdx.x;
    const int lane = tid & 63;
    const int wave = tid >> 6;
    const int quad = lane >> 4;
    const int l16  = lane & 15;
    const int blk  = blockIdx.x;     // 0..63

    // ---- one-time: pin this block's weight slabs in LDS ----
    for (int i = tid; i < 32 * 128; i += 256) {      // 128 16B-chunks per row
        const int r = i >> 7, c = (i & 127) * 8;
        *(bf16x8*)(&Wzr_s[r * WPAD + c]) =
            *(const bf16x8*)(WzrT + (size_t)(blk * 32 + r) * 1024 + c);
    }
    for (int i = tid; i < 16 * 128; i += 256) {
        const int r = i >> 7, c = (i & 127) * 8;
        *(bf16x8*)(&Whh_s[r * WPAD + c]) =
            *(const bf16x8*)(WhhT + (size_t)(blk * 16 + r) * 1024 + c);
    }
    __syncthreads();

    cg::grid_group grid = cg::this_grid();

    for (int t = 0; t < T; ++t) {
        const float* Xzr = Xzrh + (size_t)t * 32 * 3072;

        // ================= phase 1: ZR = Xzr + H @ W_hzr =================
        {
            const int tn = wave & 1;          // n-tile within block (0..1)
            const int mt = wave >> 1;         // m-tile (batch rows 0-15 / 16-31)
            const int ng = blk * 32 + tn * 16 + l16;   // global col 0..2047
            const u16* Arow = Hbf + (mt * 16 + l16) * 1024 + quad * 8;
            const u16* Brow = &Wzr_s[(tn * 16 + l16) * WPAD + quad * 8];
            f32x4 acc = (f32x4){0,0,0,0}, acc2 = (f32x4){0,0,0,0};
#pragma unroll 8
            for (int kb = 0; kb < 32; kb += 2) {
                acc  = mfma16(*(const bf16x8*)(Arow + kb * 32),
                              *(const bf16x8*)(Brow + kb * 32), acc);
                acc2 = mfma16(*(const bf16x8*)(Arow + kb * 32 + 32),
                              *(const bf16x8*)(Brow + kb * 32 + 32), acc2);
            }
            acc += acc2;
#pragma unroll
            for (int r = 0; r < 4; r++) {
                const int row = mt * 16 + quad * 4 + r;
                const float v = acc[r] + Xzr[row * 3072 + ng];
                if (ng < 1024) {              // wave-uniform (blocks 0-31)
                    Zbuf[row * 1024 + ng] = sigm(v);
                } else {                      // blocks 32-63
                    const int m_ = ng - 1024;
                    RHbf[row * 1024 + m_] = f2bf(sigm(v) * Hf[row * 1024 + m_]);
                }
            }
        }
        grid.sync();

        // ====== phase 2: Ht = tanh(Xh + RH @ W_hh); Hn = Z*H + (1-Z)*Ht ======
        {
            const int mt = wave & 1;          // m-tile
            const int kh = wave >> 1;         // k-half (0: k<512, 1: k>=512)
            const int n  = blk * 16 + l16;    // global col 0..1023
            const u16* Arow = RHbf + (mt * 16 + l16) * 1024 + kh * 512 + quad * 8;
            const u16* Brow = &Whh_s[l16 * WPAD + kh * 512 + quad * 8];
            f32x4 acc = (f32x4){0,0,0,0}, acc2 = (f32x4){0,0,0,0};
#pragma unroll 8
            for (int kb = 0; kb < 16; kb += 2) {
                acc  = mfma16(*(const bf16x8*)(Arow + kb * 32),
                              *(const bf16x8*)(Brow + kb * 32), acc);
                acc2 = mfma16(*(const bf16x8*)(Arow + kb * 32 + 32),
                              *(const bf16x8*)(Brow + kb * 32 + 32), acc2);
            }
            acc += acc2;
            if (kh == 1) *(f32x4*)(&red[mt][lane][0]) = acc;
            __syncthreads();
            if (kh == 0) {
                acc += *(const f32x4*)(&red[mt][lane][0]);
                u16* Hs_t = Hsbf + (size_t)t * 32 * 1024;
#pragma unroll
                for (int r = 0; r < 4; r++) {
                    const int row = mt * 16 + quad * 4 + r;
                    const float v  = acc[r] + Xzr[row * 3072 + 2048 + n];
                    const float ht = tanhf(v);
                    const float z  = Zbuf[row * 1024 + n];
                    const float hp = Hf[row * 1024 + n];
                    const float hn = z * hp + (1.f - z) * ht;
                    Hf[row * 1024 + n] = hn;
                    const u16 hb = f2bf(hn);
                    Hbf[row * 1024 + n]  = hb;
                    Hs_t[row * 1024 + n] = hb;
                }
            }
        }
        grid.sync();
    }
}

// ---------------------------------------------------------------------------
// fp32 -> bf16 row cast with K padding: dst[r*Kp+k] = k<K0 ? bf(src[r*K0+k]) : 0
// ---------------------------------------------------------------------------
__global__ void k_cast_pad(const float* __restrict__ src, u16* __restrict__ dst,
                           int rows, int K0, int Kp)
{
    const size_t total = (size_t)rows * (size_t)(Kp >> 2);
    for (size_t idx = (size_t)blockIdx.x * blockDim.x + threadIdx.x;
         idx < total; idx += (size_t)gridDim.x * blockDim.x) {
        const int kq = (int)(idx % (size_t)(Kp >> 2));
        const int r  = (int)(idx / (size_t)(Kp >> 2));
        const int k  = kq << 2;
        u16x4 o;
        if (k + 3 < K0) {
            const float4 v = *(const float4*)(src + (size_t)r * K0 + k);
            o[0] = f2bf(v.x); o[1] = f2bf(v.y); o[2] = f2bf(v.z); o[3] = f2bf(v.w);
        } else {
#pragma unroll
            for (int i = 0; i < 4; i++)
                o[i] = (k + i < K0) ? f2bf(src[(size_t)r * K0 + k + i]) : (u16)0;
        }
        *(u16x4*)(dst + (size_t)r * Kp + k) = o;
    }
}

// ---------------------------------------------------------------------------
// Transpose + cast: dst[(rowOff+n)*Kp + k] = (k<K0 && n<N0) ? bf(src[k*N0+n]) : 0
// grid: (Kp/32, Nrows/32), block (32,8). Kp, Nrows multiples of 32.
// ---------------------------------------------------------------------------
__global__ void k_transpose_cast(const float* __restrict__ src, u16* __restrict__ dst,
                                 int K0, int N0, int Kp, int rowOff)
{
    __shared__ float tile[32][33];
    const int kb = blockIdx.x * 32, nb = blockIdx.y * 32;
    const int tx = threadIdx.x, ty = threadIdx.y;
#pragma unroll
    for (int i = 0; i < 4; i++) {
        const int k = kb + ty + i * 8, n = nb + tx;
        tile[ty + i * 8][tx] = (k < K0 && n < N0) ? src[(size_t)k * N0 + n] : 0.f;
    }
    __syncthreads();
#pragma unroll
    for (int i = 0; i < 4; i++) {
        const int n = nb + ty + i * 8, k = kb + tx;
        dst[(size_t)(rowOff + n) * Kp + k] = f2bf(tile[tx][ty + i * 8]);
    }
}

__global__ void k_bias_cat(const float* __restrict__ bz, const float* __restrict__ br,
                           const float* __restrict__ bh, float* __restrict__ bcat)
{
    const int i = blockIdx.x * 256 + threadIdx.x;
    if (i < 1024) bcat[i] = bz[i];
    else if (i < 2048) bcat[i] = br[i - 1024];
    else if (i < 3072) bcat[i] = bh[i - 2048];
}

__global__ void k_h0(const float* __restrict__ H0, float* __restrict__ Hf,
                     u16* __restrict__ Hbf)
{
    const int i = blockIdx.x * 256 + threadIdx.x;
    if (i < 32 * 1024) { float v = H0[i]; Hf[i] = v; Hbf[i] = f2bf(v); }
}

// ---------------------------------------------------------------------------
extern "C" void kernel_launch(void* const* d_in, const int* in_sizes, int n_in,
                              void* d_out, int out_size, void* d_ws, size_t ws_size,
                              hipStream_t stream)
{
    const float* inputs = (const float*)d_in[0];
    const float* H0     = (const float*)d_in[1];
    const float* W_xz   = (const float*)d_in[2];
    const float* W_hz   = (const float*)d_in[3];
    const float* b_z    = (const float*)d_in[4];
    const float* W_xr   = (const float*)d_in[5];
    const float* W_hr   = (const float*)d_in[6];
    const float* b_r    = (const float*)d_in[7];
    const float* W_xh   = (const float*)d_in[8];
    const float* W_hh   = (const float*)d_in[9];
    const float* b_h    = (const float*)d_in[10];
    const float* W_hq   = (const float*)d_in[11];
    const float* b_q    = (const float*)d_in[12];
    float* out = (float*)d_out;

    constexpr int T = 128, B = 32, V = 10000, H = 1024;
    constexpr int Vp = 10016;               // K padded to %32
    constexpr int MB = T * B;               // 4096
    constexpr int Np3 = 10112;              // W_hq^T rows padded to %128

    char* p = (char*)d_ws;
    auto alloc = [&](size_t bytes) -> void* {
        void* q = (void*)p; p += (bytes + 255) & ~(size_t)255; return q;
    };
    u16*   Abf  = (u16*)  alloc((size_t)MB * Vp * 2);     // inputs bf16, padded
    u16*   WxT  = (u16*)  alloc((size_t)3072 * Vp * 2);   // [3H][Vp]
    float* Xzrh = (float*)alloc((size_t)MB * 3072 * 4);
    u16*   Hsbf = (u16*)  alloc((size_t)MB * H * 2);
    u16*   WzrT = (u16*)  alloc((size_t)2048 * H * 2);
    u16*   WhhT = (u16*)  alloc((size_t)H * H * 2);
    u16*   WhqT = (u16*)  alloc((size_t)Np3 * H * 2);
    float* bcat = (float*)alloc(3072 * 4);
    float* Hf   = (float*)alloc((size_t)B * H * 4);
    u16*   Hbf  = (u16*)  alloc((size_t)B * H * 2);
    float* Zbuf = (float*)alloc((size_t)B * H * 4);
    u16*   RHbf = (u16*)  alloc((size_t)B * H * 2);

    // --- casts / transposes ---
    {
        size_t total = (size_t)MB * (Vp / 4);
        int blocks = (int)((total + 255) / 256);
        k_cast_pad<<<blocks, 256, 0, stream>>>(inputs, Abf, MB, V, Vp);
    }
    dim3 tb(32, 8);
    k_transpose_cast<<<dim3(Vp / 32, H / 32), tb, 0, stream>>>(W_xz, WxT, V, H, Vp, 0);
    k_transpose_cast<<<dim3(Vp / 32, H / 32), tb, 0, stream>>>(W_xr, WxT, V, H, Vp, 1024);
    k_transpose_cast<<<dim3(Vp / 32, H / 32), tb, 0, stream>>>(W_xh, WxT, V, H, Vp, 2048);
    k_transpose_cast<<<dim3(H / 32, H / 32), tb, 0, stream>>>(W_hz, WzrT, H, H, H, 0);
    k_transpose_cast<<<dim3(H / 32, H / 32), tb, 0, stream>>>(W_hr, WzrT, H, H, H, 1024);
    k_transpose_cast<<<dim3(H / 32, H / 32), tb, 0, stream>>>(W_hh, WhhT, H, H, H, 0);
    k_transpose_cast<<<dim3(H / 32, Np3 / 32), tb, 0, stream>>>(W_hq, WhqT, H, V, H, 0);
    k_bias_cat<<<12, 256, 0, stream>>>(b_z, b_r, b_h, bcat);
    k_h0<<<128, 256, 0, stream>>>(H0, Hf, Hbf);

    // --- GEMM1: Xzrh = inputs @ [W_xz|W_xr|W_xh] + [b_z|b_r|b_h] ---
    gemm_bt<<<dim3(3072 / 128, MB / 128), 256, 0, stream>>>(
        Abf, WxT, bcat, Xzrh, MB, 3072, Vp, 3072, 3072);

    // --- recurrence: one persistent cooperative kernel, 128 steps ---
    {
        int Tloc = T;
        void* kargs[] = { (void*)&WzrT, (void*)&WhhT, (void*)&Xzrh, (void*)&Hf,
                          (void*)&Hbf, (void*)&Zbuf, (void*)&RHbf, (void*)&Hsbf,
                          (void*)&Tloc };
        hipLaunchCooperativeKernel((const void*)k_recurrence, dim3(64), dim3(256),
                                   kargs, 0, stream);
    }

    // --- GEMM3: out = Hs @ W_hq + b_q ---
    gemm_bt<<<dim3(Np3 / 128, MB / 128), 256, 0, stream>>>(
        Hsbf, WhqT, b_q, out, MB, Np3, H, V, V);

    // --- H_last ---
    hipMemcpyAsync(out + (size_t)MB * V, Hf, (size_t)B * H * 4,
                   hipMemcpyDeviceToDevice, stream);
}